// Round 12
// baseline (213.103 us; speedup 1.0000x reference)
//
#include <hip/hip_runtime.h>

// ---- problem constants (match reference) ----
#define BEV_W    512
#define BEV_H    512
#define SCALE_XY (BEV_W * BEV_H)      // 262144
#define NPTS     400000
#define NFEAT    64
#define BATCH    2
#define NSEG     (BATCH * SCALE_XY)   // 524288

// ws layout: [0 .. NSEG*2) u64 : per-voxel packed sums {xy, z|cnt}
//            then           f32 : bev image, NSEG*64 floats
#define SUMS_U64S  ((size_t)NSEG * 2)
#define SUMS_BYTES (SUMS_U64S * sizeof(unsigned long long))
#define BEV_FLOATS ((size_t)NSEG * 64)

// fixed-point: scale 2^19 (quant 1.9e-6), biases keep per-point fields
// non-negative; 32-bit field sums safe to >50 points/voxel (max here ~9).
#define FP_SCALE 524288.0f
#define FP_INV   (1.0f / 524288.0f)
#define BIAS_XY  (1 << 25)
#define BIAS_Z   (1 << 22)

// XLA lowers x / 0.2f to x * (1/0.2f); 1/0.2f rounds to EXACTLY 5.0f.
__device__ __forceinline__ float coordf(float v) {
    return (v + 51.2f) * 5.0f;
}
__device__ __forceinline__ int vox_coord(float v) {
    return (int)floorf(coordf(v));
}

// ---------------- kernel A: packed sums + touched-line bev zeroing ----------
// 2 threads per point: each zeroes 128 B of the point's bev row (replaces the
// 134 MB global memset; same-voxel races all write 0 = benign), then issues
// ONE u64 atomic (even: {x,y}, odd: {z,count}).
__global__ void __launch_bounds__(256)
kA_scatter_sums(const float* __restrict__ pts,
                unsigned long long* __restrict__ sumsc,
                float4* __restrict__ bev4) {
    int gid = blockIdx.x * blockDim.x + threadIdx.x;
    int p = gid >> 1;
    if (p >= NPTS) return;
    const float* pp = pts + (size_t)p * 6;
    float b = pp[0], x = pp[1], y = pp[2];
    int cx = vox_coord(x);
    int cy = vox_coord(y);
    int flat = (int)b * SCALE_XY + cy * BEV_W + cx;
    int half = gid & 1;

    // zero this point's bev half-row (8 x float4 = 128 B); stores overlap the
    // atomic-bound tail of the kernel and keep the lines hot for kB.
    float4 z4 = make_float4(0.f, 0.f, 0.f, 0.f);
    float4* dst = bev4 + (size_t)flat * 16 + half * 8;
    #pragma unroll
    for (int i = 0; i < 8; ++i) dst[i] = z4;

    if (half == 0) {
        unsigned int ex = (unsigned int)(__float2int_rn(x * FP_SCALE) + BIAS_XY);
        unsigned int ey = (unsigned int)(__float2int_rn(y * FP_SCALE) + BIAS_XY);
        unsigned long long uxy = ((unsigned long long)ex << 32) | ey;
        atomicAdd(&sumsc[(size_t)flat * 2 + 0], uxy);
    } else {
        float z = pp[3];
        unsigned int ez = (unsigned int)(__float2int_rn(z * FP_SCALE) + BIAS_Z);
        unsigned long long uzc = ((unsigned long long)ez << 32) | 1ull;
        atomicAdd(&sumsc[(size_t)flat * 2 + 1], uzc);
    }
}

// ---------------- kernel B: K points per wave, lane = feature ----------------
#define KB_K 8
__global__ void __launch_bounds__(256)
kB_pillar_max(const float* __restrict__ pts, const float* __restrict__ Wm,
              const float* __restrict__ gamma, const float* __restrict__ beta,
              const float* __restrict__ bmean, const float* __restrict__ bvar,
              const unsigned long long* __restrict__ sumsc,
              unsigned int* __restrict__ bev) {
    __shared__ float sW[10 * 64];
    __shared__ float sScale[64];
    __shared__ float sShift[64];
    int tid = threadIdx.x;
    for (int i = tid; i < 640; i += 256) sW[i] = Wm[i];
    if (tid < 64) {
        float sc = gamma[tid] * rsqrtf(bvar[tid] + 0.001f);
        sScale[tid] = sc;
        sShift[tid] = beta[tid] - bmean[tid] * sc;
    }
    __syncthreads();

    int wid  = tid >> 6;
    int lane = tid & 63;
    int p0 = (blockIdx.x * 4 + wid) * KB_K;
    p0 = __builtin_amdgcn_readfirstlane(p0);          // SGPR base
    if (p0 >= NPTS) return;

    float rec[6 * KB_K];
    const float* pbase = pts + (size_t)p0 * 6;
    #pragma unroll
    for (int i = 0; i < 6 * KB_K; ++i) rec[i] = pbase[i];

    int                flats[KB_K];
    unsigned long long u0[KB_K], u1[KB_K];
    #pragma unroll
    for (int k = 0; k < KB_K; ++k) {
        float x = rec[6 * k + 1], y = rec[6 * k + 2];
        int b  = (int)rec[6 * k + 0];
        int cx = vox_coord(x);
        int cy = vox_coord(y);
        int fl = b * SCALE_XY + cy * BEV_W + cx;
        fl = __builtin_amdgcn_readfirstlane(fl);
        flats[k] = fl;
        const unsigned long long* sv = sumsc + (size_t)fl * 2;
        u0[k] = sv[0]; u1[k] = sv[1];
    }

    const float XOFF = 0.1f + -51.2f;   // voxel/2 + pc_min, f32 fold
    int j = lane;
    #pragma unroll
    for (int k = 0; k < KB_K; ++k) {
        float x = rec[6 * k + 1], y = rec[6 * k + 2], z = rec[6 * k + 3];
        float it = rec[6 * k + 4], tt = rec[6 * k + 5];
        int cx = vox_coord(x);
        int cy = vox_coord(y);

        // decode packed fixed-point sums
        int n = (int)(unsigned int)u1[k];
        long long xs = (long long)(u0[k] >> 32)           - (long long)n * BIAS_XY;
        long long ys = (long long)(u0[k] & 0xffffffffULL) - (long long)n * BIAS_XY;
        long long zs = (long long)(u1[k] >> 32)           - (long long)n * BIAS_Z;
        float c = fmaxf((float)n, 1.0f);
        float inv = __builtin_amdgcn_rcpf(c);   // 1-ulp; error ~1e-7 << 0.266
        float mx = ((float)xs * FP_INV) * inv;
        float my = ((float)ys * FP_INV) * inv;
        float mz = ((float)zs * FP_INV) * inv;

        float fcx = x - ((float)cx * 0.2f + XOFF);
        float fcy = y - ((float)cy * 0.2f + XOFF);

        float h = x  * sW[0 * 64 + j]
                + y  * sW[1 * 64 + j]
                + z  * sW[2 * 64 + j]
                + it * sW[3 * 64 + j]
                + tt * sW[4 * 64 + j]
                + (x - mx) * sW[5 * 64 + j]
                + (y - my) * sW[6 * 64 + j]
                + (z - mz) * sW[7 * 64 + j]
                + fcx * sW[8 * 64 + j]
                + fcy * sW[9 * 64 + j];

        h = h * sScale[j] + sShift[j];
        h = fmaxf(h, 0.0f);

        // touched voxels were zeroed by kA; stored values >= 0, so h == 0 is
        // a no-op max: skip it.
        if (h > 0.0f)
            atomicMax((int*)(bev + (size_t)flats[k] * 64 + j), __float_as_int(h));
    }
}

// ---------------- kernel C: K points per wave, bilinear gather ----------------
// Corners of empty voxels (cnt==0) may hold garbage (bev is never globally
// zeroed): mask with cnt>0, exactly reference's where(cnt>0, pill, 0).
#define KC_K 8
__global__ void __launch_bounds__(256)
kC_bilinear(const float* __restrict__ pts, const float* __restrict__ bev,
            const unsigned int* __restrict__ sums32,   // u32 view of sumsc
            float* __restrict__ out) {
    int tid  = threadIdx.x;
    int wid  = tid >> 6;
    int lane = tid & 63;
    int p0 = (blockIdx.x * 4 + wid) * KC_K;
    p0 = __builtin_amdgcn_readfirstlane(p0);
    if (p0 >= NPTS) return;

    float rec[6 * KC_K];
    const float* pbase = pts + (size_t)p0 * 6;
    #pragma unroll
    for (int i = 0; i < 6 * KC_K; ++i) rec[i] = pbase[i];

    float Ia[KC_K], Ib[KC_K], Ic[KC_K], Id[KC_K];
    unsigned int ca[KC_K], cb[KC_K], cc[KC_K], cd[KC_K];
    float wa[KC_K], wb[KC_K], wc[KC_K], wd[KC_K];
    #pragma unroll
    for (int k = 0; k < KC_K; ++k) {
        float x = rec[6 * k + 1], y = rec[6 * k + 2];
        int b = (int)rec[6 * k + 0];
        float px = coordf(x);
        float py = coordf(y);
        int fx = (int)floorf(px);
        int fy = (int)floorf(py);
        int x0 = min(max(fx, 0), BEV_W - 1);
        int x1 = min(max(fx + 1, 0), BEV_W - 1);
        int y0 = min(max(fy, 0), BEV_H - 1);
        int y1 = min(max(fy + 1, 0), BEV_H - 1);

        wa[k] = ((float)x1 - px) * ((float)y1 - py);
        wb[k] = ((float)x1 - px) * (py - (float)y0);
        wc[k] = (px - (float)x0) * ((float)y1 - py);
        wd[k] = (px - (float)x0) * (py - (float)y0);

        int fA = b * SCALE_XY + y0 * BEV_W + x0;
        int fB = b * SCALE_XY + y1 * BEV_W + x0;
        int fC = b * SCALE_XY + y0 * BEV_W + x1;
        int fD = b * SCALE_XY + y1 * BEV_W + x1;

        // cnt = low dword of sumsc[flat*2+1]  ->  u32 index flat*4 + 2
        ca[k] = sums32[(size_t)fA * 4 + 2];
        cb[k] = sums32[(size_t)fB * 4 + 2];
        cc[k] = sums32[(size_t)fC * 4 + 2];
        cd[k] = sums32[(size_t)fD * 4 + 2];

        Ia[k] = bev[(size_t)fA * 64 + lane];
        Ib[k] = bev[(size_t)fB * 64 + lane];
        Ic[k] = bev[(size_t)fC * 64 + lane];
        Id[k] = bev[(size_t)fD * 64 + lane];
    }

    #pragma unroll
    for (int k = 0; k < KC_K; ++k) {
        float A = ca[k] ? Ia[k] : 0.0f;
        float B = cb[k] ? Ib[k] : 0.0f;
        float C = cc[k] ? Ic[k] : 0.0f;
        float D = cd[k] ? Id[k] : 0.0f;
        float v = A * wa[k] + B * wb[k] + C * wc[k] + D * wd[k];
        __builtin_nontemporal_store(v, &out[(size_t)(p0 + k) * 64 + lane]);
    }
}

extern "C" void kernel_launch(void* const* d_in, const int* in_sizes, int n_in,
                              void* d_out, int out_size, void* d_ws, size_t ws_size,
                              hipStream_t stream) {
    const float* pts   = (const float*)d_in[0];
    const float* Wm    = (const float*)d_in[1];
    const float* gamma = (const float*)d_in[2];
    const float* beta  = (const float*)d_in[3];
    const float* bmean = (const float*)d_in[4];
    const float* bvar  = (const float*)d_in[5];
    float* out = (float*)d_out;

    unsigned long long* sumsc = (unsigned long long*)d_ws;
    float* bev = (float*)((char*)d_ws + SUMS_BYTES);

    // zero ONLY the packed sums (8.4 MB; integer atomicAdd is not idempotent
    // across replays). bev is zeroed lazily per touched voxel inside kA;
    // untouched voxels are masked via cnt in kC.
    (void)hipMemsetAsync(d_ws, 0, SUMS_BYTES, stream);

    // kA: 2 threads/point (1 u64 atomic + 128 B bev zeroing each)
    kA_scatter_sums<<<(2 * NPTS) / 256, 256, 0, stream>>>(pts, sumsc, (float4*)bev);
    // kB: 4 waves/block x 8 pts/wave -> 12500 blocks (exact)
    kB_pillar_max<<<NPTS / (4 * KB_K), 256, 0, stream>>>(pts, Wm, gamma, beta,
                                                         bmean, bvar, sumsc,
                                                         (unsigned int*)bev);
    // kC: 4 waves/block x 8 pts/wave -> 12500 blocks (exact)
    kC_bilinear<<<NPTS / (4 * KC_K), 256, 0, stream>>>(pts, (const float*)bev,
                                                       (const unsigned int*)sumsc,
                                                       out);
}